// Round 7
// baseline (796.600 us; speedup 1.0000x reference)
//
#include <hip/hip_runtime.h>
#include <math.h>

// Problem constants
#define Bb 4
#define Ss 4096
#define Hh 1024
#define Mm 1024
#define Ee 16
#define CAPk 512            // ceil(2.0 * 4096 / 16)

typedef unsigned short u16;
typedef __attribute__((ext_vector_type(8))) short short8;
typedef __attribute__((ext_vector_type(4))) float floatx4;
typedef __attribute__((ext_vector_type(4))) unsigned short ushort4v;

__device__ __forceinline__ float silu_f(float x) {
    return x / (1.0f + expf(-x));
}

// fp32 -> bf16 (RNE)
__device__ __forceinline__ u16 f2b(float x) {
    union { float f; unsigned u; } v; v.f = x;
    unsigned r = (v.u + 0x7fffu + ((v.u >> 16) & 1u)) >> 16;
    return (u16)r;
}

// async 16B global->LDS (wave-uniform LDS base + lane*16)
__device__ __forceinline__ void gl_lds16(const void* g, void* l) {
    __builtin_amdgcn_global_load_lds((const __attribute__((address_space(1))) void*)g,
                                     (__attribute__((address_space(3))) void*)l, 16, 0, 0);
}

// ---------------- fused convert + router ----------------
// blocks [0,256): router scores (64 tokens/block) -- first so their latency
// hides under the convert stream. blocks [256,16640): convert fp32 -> bf16.

__global__ __launch_bounds__(256)
void conv_router(const float* __restrict__ hidden, u16* __restrict__ Xb,
                 const float* __restrict__ hsu,
                 const float* __restrict__ gate_w,
                 const float* __restrict__ timestep,
                 float* __restrict__ scores) {
    const int t = threadIdx.x;
    if (blockIdx.x >= 256) {
        int i = ((blockIdx.x - 256) * 256 + t) * 4;
        float4 v = *(const float4*)(hidden + i);
        ushort4v o = { f2b(v.x), f2b(v.y), f2b(v.z), f2b(v.w) };
        *(ushort4v*)(Xb + i) = o;
        return;
    }
    __shared__ float Xs[64 * 64];   // 16 KB, swizzled 16B chunks
    __shared__ float Gs[64 * 16];   // 4 KB
    const int rbid = blockIdx.x;
    const int row0 = rbid * 64;              // token base (never crosses b: 4096%64==0)
    const int b = row0 >> 12;
    const int wave = t >> 6, lane = t & 63;
    const int e0 = wave * 4;
    const float* gw2 = gate_w + (size_t)Hh * Ee;   // [k][16] second-half rows

    // inline tlogit for this wave's 4 experts
    float tl0 = 0.f, tl1 = 0.f, tl2 = 0.f, tl3 = 0.f;
    {
        const float* tsrow = timestep + (size_t)b * Hh;
#pragma unroll
        for (int j = 0; j < 16; ++j) {
            int h = lane + 64 * j;
            float tv = tsrow[h];
            const float* gw = gate_w + (size_t)h * Ee + e0;
            tl0 += tv * gw[0]; tl1 += tv * gw[1]; tl2 += tv * gw[2]; tl3 += tv * gw[3];
        }
#pragma unroll
        for (int off = 32; off; off >>= 1) {
            tl0 += __shfl_xor(tl0, off); tl1 += __shfl_xor(tl1, off);
            tl2 += __shfl_xor(tl2, off); tl3 += __shfl_xor(tl3, off);
        }
    }

    float acc0 = 0.f, acc1 = 0.f, acc2 = 0.f, acc3 = 0.f;

    for (int k0 = 0; k0 < Hh; k0 += 64) {
        __syncthreads();
#pragma unroll
        for (int r = 0; r < 4; ++r) {
            int tok = r * 16 + (t >> 4);
            int cslot = t & 15;                 // dest 16B slot within row
            int g = cslot ^ (tok & 15);         // source chunk (swizzle via source)
            const float* src = hsu + (size_t)(row0 + tok) * Hh + k0 + g * 4;
            char* dst = (char*)Xs + r * 4096 + wave * 1024;   // wave-uniform
            gl_lds16(src, dst);
        }
        {
            const float* src = gw2 + (size_t)k0 * Ee + t * 4;
            char* dst = (char*)Gs + wave * 1024;
            gl_lds16(src, dst);
        }
        __syncthreads();
#pragma unroll
        for (int kk = 0; kk < 64; kk += 4) {
            int slot = (kk >> 2) ^ (lane & 15);
            float4 a = *(const float4*)&Xs[lane * 64 + slot * 4];
            float4 g0 = *(const float4*)&Gs[(kk + 0) * Ee + e0];
            float4 g1 = *(const float4*)&Gs[(kk + 1) * Ee + e0];
            float4 g2 = *(const float4*)&Gs[(kk + 2) * Ee + e0];
            float4 g3 = *(const float4*)&Gs[(kk + 3) * Ee + e0];
            acc0 += a.x * g0.x; acc0 += a.y * g1.x; acc0 += a.z * g2.x; acc0 += a.w * g3.x;
            acc1 += a.x * g0.y; acc1 += a.y * g1.y; acc1 += a.z * g2.y; acc1 += a.w * g3.y;
            acc2 += a.x * g0.z; acc2 += a.y * g1.z; acc2 += a.z * g2.z; acc2 += a.w * g3.z;
            acc3 += a.x * g0.w; acc3 += a.y * g1.w; acc3 += a.z * g2.w; acc3 += a.w * g3.w;
        }
    }
    const int s = (row0 + lane) & (Ss - 1);
    float l0 = acc0 + tl0;
    float l1 = acc1 + tl1;
    float l2 = acc2 + tl2;
    float l3 = acc3 + tl3;
    scores[((size_t)(b * Ee + e0 + 0)) * Ss + s] = 1.f / (1.f + expf(-l0));
    scores[((size_t)(b * Ee + e0 + 1)) * Ss + s] = 1.f / (1.f + expf(-l1));
    scores[((size_t)(b * Ee + e0 + 2)) * Ss + s] = 1.f / (1.f + expf(-l2));
    scores[((size_t)(b * Ee + e0 + 3)) * Ss + s] = 1.f / (1.f + expf(-l3));
}

// Radix top-k, 1024 threads (4 elems/thread), wave-parallel scans.
// Output: dense rank[be][s] = capacity slot (or -1 if not selected).
__global__ __launch_bounds__(1024)
void topk_kernel(const float* __restrict__ scores,
                 int* __restrict__ rank) {
    const int be = blockIdx.x;
    const float* sc = scores + (size_t)be * Ss;
    int* rk = rank + (size_t)be * Ss;
    const int t = threadIdx.x;
    const int lane = t & 63, w = t >> 6;     // 16 waves
    __shared__ unsigned hist[256];
    __shared__ unsigned wtot[16];
    __shared__ unsigned sh_prefix;
    __shared__ int sh_need;
    __shared__ unsigned cnt_gt;

#pragma unroll
    for (int i = 0; i < 4; ++i) rk[t * 4 + i] = -1;

    unsigned vu[4];
#pragma unroll
    for (int i = 0; i < 4; ++i) vu[i] = __float_as_uint(sc[t * 4 + i]);

    unsigned prefix = 0;
    int need = CAPk;
    for (int pass = 0; pass < 4; ++pass) {
        const int shift = 24 - 8 * pass;
        if (t < 256) hist[t] = 0;
        __syncthreads();
#pragma unroll
        for (int i = 0; i < 4; ++i) {
            unsigned u = vu[i];
            bool ok = (pass == 0) || ((u >> (shift + 8)) == prefix);
            if (ok) atomicAdd(&hist[(u >> shift) & 255u], 1u);
        }
        __syncthreads();
        unsigned hval = (t < 256) ? hist[t] : 0u;
        unsigned s = hval;
#pragma unroll
        for (int d = 1; d < 64; d <<= 1) {
            unsigned o = __shfl_down(s, d);
            if (lane + d < 64) s += o;
        }
        if (lane == 0 && w < 4) wtot[w] = s;
        __syncthreads();
        if (t < 256) {
#pragma unroll
            for (int w2 = 0; w2 < 4; ++w2)
                if (w2 > w) s += wtot[w2];
            unsigned Snext = s - hval;
            if (s >= (unsigned)need && Snext < (unsigned)need) {
                sh_prefix = (prefix << 8) | (unsigned)t;
                sh_need = need - (int)Snext;
            }
        }
        __syncthreads();
        prefix = sh_prefix;
        need = sh_need;
        __syncthreads();
    }
    const unsigned T = prefix;
    const int need_eq = need;
    const unsigned ngt = (unsigned)(CAPk - need_eq);

    int myeq = 0;
#pragma unroll
    for (int i = 0; i < 4; ++i) myeq += (vu[i] == T) ? 1 : 0;
    unsigned e = (unsigned)myeq;
#pragma unroll
    for (int d = 1; d < 64; d <<= 1) {
        unsigned o = __shfl_up(e, d);
        if (lane >= d) e += o;
    }
    if (lane == 63) wtot[w] = e;
    if (t == 0) cnt_gt = 0;
    __syncthreads();
    unsigned eqr = e - (unsigned)myeq;
#pragma unroll
    for (int w2 = 0; w2 < 16; ++w2)
        if (w2 < w) eqr += wtot[w2];
#pragma unroll
    for (int i = 0; i < 4; ++i) {
        unsigned u = vu[i];
        int s = t * 4 + i;
        if (u > T) {
            unsigned slot = atomicAdd(&cnt_gt, 1u);
            rk[s] = (int)slot;
        } else if (u == T) {
            if ((int)eqr < need_eq) {
                rk[s] = (int)(ngt + eqr);
            }
            eqr++;
        }
    }
}

// Dense, atomic-free routing build: per-token normalization + slot map + inverse map.
__global__ __launch_bounds__(256)
void route_build(const float* __restrict__ scores, const int* __restrict__ rank,
                 int* __restrict__ slot_token, float* __restrict__ slot_w,
                 int* __restrict__ cnt, int* __restrict__ inv) {
    const int token = blockIdx.x * 256 + threadIdx.x;   // 0..16383
    const int b = token >> 12, s = token & (Ss - 1);
    int rr[16];
    float gg[16];
    float sum = 0.f;
#pragma unroll
    for (int e = 0; e < 16; ++e) {
        size_t idx = (size_t)(b * Ee + e) * Ss + s;
        int r = rank[idx];
        rr[e] = r;
        float g = (r >= 0) ? scores[idx] : 0.f;
        gg[e] = g;
        sum += g;
    }
    int pos = 0;
#pragma unroll
    for (int e = 0; e < 16; ++e) {
        if (rr[e] >= 0) {
            float wv = gg[e] / (sum + 1e-12f);
            int o = (e * Bb + b) * CAPk + rr[e];
            slot_token[o] = token;
            slot_w[o] = wv;
            inv[token * 16 + pos] = o;
            ++pos;
        }
    }
    cnt[token] = pos;
}

// dedicated high-occupancy combine: out[token] += sum_j eo[slot_j]
__global__ __launch_bounds__(256)
void combine_kernel(const int* __restrict__ cnt, const int* __restrict__ inv,
                    const float* __restrict__ eo, float* __restrict__ out) {
    const int token = blockIdx.x;           // 16384
    const int k = cnt[token];               // wave-uniform scalar
    if (k == 0) return;
    const int col = threadIdx.x * 4;
    const size_t rowoff = (size_t)token * 1024 + col;
    float4 acc = *(const float4*)(out + rowoff);
    for (int j = 0; j < k; ++j) {
        int slot = inv[token * 16 + j];     // wave-uniform
        float4 v = *(const float4*)(eo + (size_t)slot * 1024 + col);
        acc.x += v.x; acc.y += v.y; acc.z += v.z; acc.w += v.w;
    }
    *(float4*)(out + rowoff) = acc;
}

// ---------------- transposes ----------------
// 64x64 tile fp32 [K][N] -> bf16 [N][K] (K total = 1024), float4 loads + short8 stores

__device__ __forceinline__ void tpose_body(const float* __restrict__ Ws, u16* __restrict__ Wd,
                                           int N, int n0, int k0, float tile[64][65], int t) {
    int lr = t >> 4, lc = (t & 15) * 4;   // 16 rows/round x 16 float4 cols
#pragma unroll
    for (int i = 0; i < 4; ++i) {
        float4 v = *(const float4*)&Ws[(size_t)(k0 + lr + i * 16) * N + n0 + lc];
        tile[lr + i * 16][lc + 0] = v.x;
        tile[lr + i * 16][lc + 1] = v.y;
        tile[lr + i * 16][lc + 2] = v.z;
        tile[lr + i * 16][lc + 3] = v.w;
    }
    __syncthreads();
    int on = t >> 2;            // output n row 0..63
    int ok0 = (t & 3) * 16;     // 16 k elems per thread
    u16 buf[16];
#pragma unroll
    for (int j = 0; j < 16; ++j) buf[j] = f2b(tile[ok0 + j][on]);
    u16* dp = &Wd[(size_t)(n0 + on) * 1024 + k0 + ok0];
    *(short8*)(dp) = *(short8*)&buf[0];
    *(short8*)(dp + 8) = *(short8*)&buf[8];
}

__global__ __launch_bounds__(256)
void transpose_bf16(const float* __restrict__ W, u16* __restrict__ Wt,
                    int N, size_t zsrc, size_t zdst) {
    __shared__ float tile[64][65];
    int n0 = blockIdx.x * 64, k0 = blockIdx.y * 64, z = blockIdx.z;
    tpose_body(W + (size_t)z * zsrc, Wt + (size_t)z * zdst, N, n0, k0, tile, threadIdx.x);
}

// All four weight transposes in ONE launch (fast path).
__global__ __launch_bounds__(256)
void transpose_all(const float* __restrict__ gate_up, const float* __restrict__ down,
                   const float* __restrict__ sh_gu, const float* __restrict__ sh_dn,
                   u16* __restrict__ Wt1r, u16* __restrict__ Wt2r,
                   u16* __restrict__ Wt1s, u16* __restrict__ Wt2s) {
    __shared__ float tile[64][65];
    const int id = blockIdx.x;
    const float* Ws; u16* Wd; int N, n0, k0;
    if (id < 8192) {                       // gate_up: 16 experts x (32 n x 16 k)
        int z = id >> 9, r = id & 511;
        n0 = (r & 31) * 64; k0 = (r >> 5) * 64; N = 2048;
        Ws = gate_up + (size_t)z * 2097152; Wd = Wt1r + (size_t)z * 2097152;
    } else if (id < 12288) {               // down: 16 experts x (16 n x 16 k)
        int i2 = id - 8192; int z = i2 >> 8, r = i2 & 255;
        n0 = (r & 15) * 64; k0 = (r >> 4) * 64; N = 1024;
        Ws = down + (size_t)z * 1048576; Wd = Wt2r + (size_t)z * 1048576;
    } else if (id < 12800) {               // shared gate_up: 32 n x 16 k
        int r = id - 12288;
        n0 = (r & 31) * 64; k0 = (r >> 5) * 64; N = 2048;
        Ws = sh_gu; Wd = Wt1s;
    } else {                               // shared down: 16 n x 16 k
        int r = id - 12800;
        n0 = (r & 15) * 64; k0 = (r >> 4) * 64; N = 1024;
        Ws = sh_dn; Wd = Wt2s;
    }
    tpose_body(Ws, Wd, N, n0, k0, tile, threadIdx.x);
}

// ---------------- MFMA GEMMs ----------------
// 512-thread / 8-wave blocks, 128M x 128N block tile (2 M-waves x 4 N-waves of 64x32),
// BK=64, global_load_lds w16, XOR swizzle.
//
// FLAT kernels (fast path) use an XCD-aware decode: xcd = blockIdx.x & 7 selects the
// expert (routed) or m-chunk (shared), so each XCD's private L2 holds ONE expert's
// working set (A-tile stripe + B panel ~ 4MB) instead of thrashing across all 16.
// Round-6 PMC evidence: routed gemm2 FETCH 279MB vs 96MB compulsory, 50% HBM, dur
// 106us == bytes/BW -> pure cross-XCD duplication.

__device__ __forceinline__ void stage_tile512(const u16* __restrict__ grow, int k0,
                                              u16* lds, int t) {
#pragma unroll
    for (int r = 0; r < 2; ++r) {
        int ci = r * 512 + t;                  // 16B chunk index 0..1023
        int m = ci >> 3;                       // row 0..127
        int c = (ci & 7) ^ (m & 7);            // source chunk (swizzle via source)
        const u16* src = grow + (size_t)m * 1024 + k0 + c * 8;
        u16* dst = lds + ((r * 8192 + (t >> 6) * 1024) >> 1);  // wave-uniform
        gl_lds16(src, dst);
    }
}

__device__ __forceinline__ void stage_rows512(const u16* __restrict__ A, const int* rid,
                                              int k0, u16* lds, int t) {
#pragma unroll
    for (int r = 0; r < 2; ++r) {
        int ci = r * 512 + t;
        int m = ci >> 3;
        int c = (ci & 7) ^ (m & 7);
        const u16* src = A + (size_t)rid[r] * 1024 + k0 + c * 8;
        u16* dst = lds + ((r * 8192 + (t >> 6) * 1024) >> 1);  // wave-uniform
        gl_lds16(src, dst);
    }
}

// GATHER: p0 = e_base, p1 = experts/dispatch (8 or 4). grid = p1*128.
// !GATHER: p0 = m_base_tiles, p1 = m_tiles/dispatch (mult of 8). grid = p1*8.
template <bool SILU_FIRST, bool GATHER>
__global__ __launch_bounds__(512, 4)
void gemm1_flat(const u16* __restrict__ A,
                const u16* __restrict__ W1t, u16* __restrict__ act,
                const int* __restrict__ slot_token, int p0, int p1) {
    __shared__ u16 lA[128 * 64];
    __shared__ u16 lB1[128 * 64];
    __shared__ u16 lB2[128 * 64];
    const int t = threadIdx.x;
    const int L = blockIdx.x;
    const int x = L & 7, j = L >> 3;
    int z = 0, bm0, n0;
    if (GATHER) {
        if (p1 == 8) { z = p0 + x; bm0 = (j >> 3) << 7; }
        else         { z = p0 + (x >> 1); bm0 = (((x & 1) << 3) + (j >> 3)) << 7; }
    } else {
        bm0 = (p0 + x * (p1 >> 3) + (j >> 3)) << 7;
    }
    n0 = (j & 7) << 7;
    const int out_base = (GATHER ? z * 2048 : 0) + bm0;
    const u16* B1row = W1t + ((size_t)(GATHER ? z * 2048 : 0) + n0) * 1024;
    const u16* B2row = B1row + (size_t)1024 * 1024;
    const int lane = t & 63;
    const int wv = t >> 6;
    const int wm = wv & 1, wn = wv >> 1;     // 2 M-waves x 4 N-waves
    const int quad = lane >> 4, l15 = lane & 15;

    int rid[2];
#pragma unroll
    for (int r = 0; r < 2; ++r) {
        int m = (t >> 3) + 64 * r;
        rid[r] = GATHER ? slot_token[z * (Bb * CAPk) + bm0 + m] : (bm0 + m);
    }

    floatx4 zero4 = {0.f, 0.f, 0.f, 0.f};
    floatx4 acc1[4][2], acc2[4][2];          // 64 AGPRs total
#pragma unroll
    for (int i = 0; i < 4; ++i)
#pragma unroll
        for (int j2 = 0; j2 < 2; ++j2) { acc1[i][j2] = zero4; acc2[i][j2] = zero4; }

    for (int k0 = 0; k0 < 1024; k0 += 64) {
        __syncthreads();
        stage_rows512(A, rid, k0, lA, t);
        stage_tile512(B1row, k0, lB1, t);
        stage_tile512(B2row, k0, lB2, t);
        __syncthreads();
#pragma unroll
        for (int kc = 0; kc < 2; ++kc) {
            short8 af[4], bf1[2], bf2[2];
#pragma unroll
            for (int mi = 0; mi < 4; ++mi) {
                int m = wm * 64 + mi * 16 + l15;
                int off = m * 64 + (((kc * 4 + quad) ^ (m & 7)) * 8);
                af[mi] = *(const short8*)&lA[off];
            }
#pragma unroll
            for (int ni = 0; ni < 2; ++ni) {
                int n = wn * 32 + ni * 16 + l15;
                int off = n * 64 + (((kc * 4 + quad) ^ (n & 7)) * 8);
                bf1[ni] = *(const short8*)&lB1[off];
                bf2[ni] = *(const short8*)&lB2[off];
            }
#pragma unroll
            for (int mi = 0; mi < 4; ++mi)
#pragma unroll
                for (int ni = 0; ni < 2; ++ni) {
                    acc1[mi][ni] = __builtin_amdgcn_mfma_f32_16x16x32_bf16(af[mi], bf1[ni], acc1[mi][ni], 0, 0, 0);
                    acc2[mi][ni] = __builtin_amdgcn_mfma_f32_16x16x32_bf16(af[mi], bf2[ni], acc2[mi][ni], 0, 0, 0);
                }
        }
    }
#pragma unroll
    for (int mi = 0; mi < 4; ++mi)
#pragma unroll
        for (int ni = 0; ni < 2; ++ni)
#pragma unroll
            for (int r = 0; r < 4; ++r) {
                int m = wm * 64 + mi * 16 + quad * 4 + r;
                int n = wn * 32 + ni * 16 + l15;
                float c1 = acc1[mi][ni][r], c2 = acc2[mi][ni][r];
                float v = SILU_FIRST ? silu_f(c1) * c2 : c1 * silu_f(c2);
                act[(size_t)(out_base + m) * 1024 + n0 + n] = f2b(v);
            }
}

// MODE 2: routed -> weighted dense eo write. p0 = e_base, p1 = experts/dispatch (8).
// MODE 0: shared -> plain out store. p0 = m_base_tiles, p1 = m_tiles/dispatch.
template <int MODE>
__global__ __launch_bounds__(512, 4)
void gemm2_flat(const u16* __restrict__ A,
                const u16* __restrict__ W2t, const float* __restrict__ slot_w,
                float* __restrict__ outp, int p0, int p1) {
    __shared__ u16 lA[128 * 64];
    __shared__ u16 lB[128 * 64];
    __shared__ float s_w[(MODE == 2) ? 128 : 1];
    const int t = threadIdx.x;
    const int L = blockIdx.x;
    const int x = L & 7, j = L >> 3;
    int z = 0, bm0, n0;
    if (MODE == 2) {
        if (p1 == 8) { z = p0 + x; bm0 = (j >> 3) << 7; }
        else         { z = p0 + (x >> 1); bm0 = (((x & 1) << 3) + (j >> 3)) << 7; }
    } else {
        bm0 = (p0 + x * (p1 >> 3) + (j >> 3)) << 7;
    }
    n0 = (j & 7) << 7;
    const int row_base = (MODE == 2 ? z * 2048 : 0) + bm0;
    const u16* Arow = A + (size_t)row_base * 1024;
    const u16* Brow = W2t + ((size_t)(MODE == 2 ? z * 1024 : 0) + n0) * 1024;
    const int lane = t & 63;
    const int wv = t >> 6;
    const int wm = wv & 1, wn = wv >> 1;     // 2 x 4
    const int quad = lane >> 4, l15 = lane & 15;

    if (MODE == 2 && t < 128) {
        s_w[t] = slot_w[row_base + t];
    }

    floatx4 zero4 = {0.f, 0.f, 0.f, 0.f};
    floatx4 acc[4][2];                       // 32 AGPRs
#pragma unroll
    for (int i = 0; i < 4; ++i)
#pragma unroll
        for (int j2 = 0; j2 < 2; ++j2) acc[i][j2] = zero4;

    for (int k0 = 0; k0 < 1024; k0 += 64) {
        __syncthreads();
        stage_tile512(Arow, k0, lA, t);
        stage_tile512(Brow, k0, lB, t);
        __syncthreads();
#pragma unroll
        for (int kc = 0; kc < 2; ++kc) {
            short8 af[4], bf[2];
#pragma unroll
            for (int mi = 0; mi < 4; ++mi) {
                int m = wm * 64 + mi * 16 + l15;
                int off = m * 64 + (((kc * 4 + quad) ^ (m & 7)) * 8);
                af[mi] = *(const short8*)&lA[off];
            }
#pragma unroll
            for (int ni = 0; ni < 2; ++ni) {
                int n = wn * 32 + ni * 16 + l15;
                int off = n * 64 + (((kc * 4 + quad) ^ (n & 7)) * 8);
                bf[ni] = *(const short8*)&lB[off];
            }
#pragma unroll
            for (int mi = 0; mi < 4; ++mi)
#pragma unroll
                for (int ni = 0; ni < 2; ++ni)
                    acc[mi][ni] = __builtin_amdgcn_mfma_f32_16x16x32_bf16(af[mi], bf[ni], acc[mi][ni], 0, 0, 0);
        }
    }
#pragma unroll
    for (int mi = 0; mi < 4; ++mi)
#pragma unroll
        for (int ni = 0; ni < 2; ++ni)
#pragma unroll
            for (int r = 0; r < 4; ++r) {
                int m = wm * 64 + mi * 16 + quad * 4 + r;
                int n = wn * 32 + ni * 16 + l15;
                float c = acc[mi][ni][r];
                if (MODE == 2) {
                    outp[(size_t)(row_base + m) * 1024 + n0 + n] = c * s_w[m];
                } else {
                    outp[(size_t)(row_base + m) * 1024 + n0 + n] = c;
                }
            }
}

// ---- legacy 3D-grid kernels (fallback paths only) ----

template <bool SILU_FIRST, bool GATHER>
__global__ __launch_bounds__(512, 4)
void gemm1_mfma(const u16* __restrict__ A, int a_row0, int zstride,
                const u16* __restrict__ W1t, u16* __restrict__ act,
                const int* __restrict__ slot_token, int e_base) {
    __shared__ u16 lA[128 * 64];
    __shared__ u16 lB1[128 * 64];
    __shared__ u16 lB2[128 * 64];
    const int t = threadIdx.x;
    const int n0 = blockIdx.x * 128;
    const int bm0 = blockIdx.y * 128;
    const int z = blockIdx.z;
    const int zb = z * zstride;
    const u16* B1row = W1t + ((size_t)z * 2048 + n0) * 1024;
    const u16* B2row = B1row + (size_t)1024 * 1024;
    const int lane = t & 63;
    const int wv = t >> 6;
    const int wm = wv & 1, wn = wv >> 1;
    const int quad = lane >> 4, l15 = lane & 15;

    int rid[2];
#pragma unroll
    for (int r = 0; r < 2; ++r) {
        int m = (t >> 3) + 64 * r;
        rid[r] = GATHER ? slot_token[(e_base + z) * (Bb * CAPk) + bm0 + m]
                        : (a_row0 + zb + bm0 + m);
    }

    floatx4 zero4 = {0.f, 0.f, 0.f, 0.f};
    floatx4 acc1[4][2], acc2[4][2];
#pragma unroll
    for (int i = 0; i < 4; ++i)
#pragma unroll
        for (int j = 0; j < 2; ++j) { acc1[i][j] = zero4; acc2[i][j] = zero4; }

    for (int k0 = 0; k0 < 1024; k0 += 64) {
        __syncthreads();
        stage_rows512(A, rid, k0, lA, t);
        stage_tile512(B1row, k0, lB1, t);
        stage_tile512(B2row, k0, lB2, t);
        __syncthreads();
#pragma unroll
        for (int kc = 0; kc < 2; ++kc) {
            short8 af[4], bf1[2], bf2[2];
#pragma unroll
            for (int mi = 0; mi < 4; ++mi) {
                int m = wm * 64 + mi * 16 + l15;
                int off = m * 64 + (((kc * 4 + quad) ^ (m & 7)) * 8);
                af[mi] = *(const short8*)&lA[off];
            }
#pragma unroll
            for (int ni = 0; ni < 2; ++ni) {
                int n = wn * 32 + ni * 16 + l15;
                int off = n * 64 + (((kc * 4 + quad) ^ (n & 7)) * 8);
                bf1[ni] = *(const short8*)&lB1[off];
                bf2[ni] = *(const short8*)&lB2[off];
            }
#pragma unroll
            for (int mi = 0; mi < 4; ++mi)
#pragma unroll
                for (int ni = 0; ni < 2; ++ni) {
                    acc1[mi][ni] = __builtin_amdgcn_mfma_f32_16x16x32_bf16(af[mi], bf1[ni], acc1[mi][ni], 0, 0, 0);
                    acc2[mi][ni] = __builtin_amdgcn_mfma_f32_16x16x32_bf16(af[mi], bf2[ni], acc2[mi][ni], 0, 0, 0);
                }
        }
    }
#pragma unroll
    for (int mi = 0; mi < 4; ++mi)
#pragma unroll
        for (int ni = 0; ni < 2; ++ni)
#pragma unroll
            for (int r = 0; r < 4; ++r) {
                int m = wm * 64 + mi * 16 + quad * 4 + r;
                int n = wn * 32 + ni * 16 + l15;
                float c1 = acc1[mi][ni][r], c2 = acc2[mi][ni][r];
                float v = SILU_FIRST ? silu_f(c1) * c2 : c1 * silu_f(c2);
                act[(size_t)(zb + bm0 + m) * 1024 + n0 + n] = f2b(v);
            }
}

template <int MODE>
__global__ __launch_bounds__(512, 4)
void gemm2_mfma(const u16* __restrict__ A, int zstride,
                const u16* __restrict__ W2t,
                const int* __restrict__ slot_token, const float* __restrict__ slot_w,
                float* __restrict__ out, int out_row0, int e_base) {
    __shared__ u16 lA[128 * 64];
    __shared__ u16 lB[128 * 64];
    __shared__ int s_tok[(MODE == 1) ? 128 : 1];
    __shared__ float s_w[(MODE == 1 || MODE == 2) ? 128 : 1];
    const int t = threadIdx.x;
    const int n0 = blockIdx.x * 128;
    const int bm0 = blockIdx.y * 128;
    const int z = blockIdx.z;
    const int zb = z * zstride;
    const u16* Arow = A + (size_t)(zb + bm0) * 1024;
    const u16* Brow = W2t + ((size_t)z * 1024 + n0) * 1024;
    const int lane = t & 63;
    const int wv = t >> 6;
    const int wm = wv & 1, wn = wv >> 1;
    const int quad = lane >> 4, l15 = lane & 15;

    if ((MODE == 1 || MODE == 2) && t < 128) {
        int gi = (e_base + z) * (Bb * CAPk) + bm0 + t;
        if (MODE == 1) s_tok[t] = slot_token[gi];
        s_w[t] = slot_w[gi];
    }

    floatx4 zero4 = {0.f, 0.f, 0.f, 0.f};
    floatx4 acc[4][2];
#pragma unroll
    for (int i = 0; i < 4; ++i)
#pragma unroll
        for (int j = 0; j < 2; ++j) acc[i][j] = zero4;

    for (int k0 = 0; k0 < 1024; k0 += 64) {
        __syncthreads();
        stage_tile512(Arow, k0, lA, t);
        stage_tile512(Brow, k0, lB, t);
        __syncthreads();
#pragma unroll
        for (int kc = 0; kc < 2; ++kc) {
            short8 af[4], bf[2];
#pragma unroll
            for (int mi = 0; mi < 4; ++mi) {
                int m = wm * 64 + mi * 16 + l15;
                int off = m * 64 + (((kc * 4 + quad) ^ (m & 7)) * 8);
                af[mi] = *(const short8*)&lA[off];
            }
#pragma unroll
            for (int ni = 0; ni < 2; ++ni) {
                int n = wn * 32 + ni * 16 + l15;
                int off = n * 64 + (((kc * 4 + quad) ^ (n & 7)) * 8);
                bf[ni] = *(const short8*)&lB[off];
            }
#pragma unroll
            for (int mi = 0; mi < 4; ++mi)
#pragma unroll
                for (int ni = 0; ni < 2; ++ni)
                    acc[mi][ni] = __builtin_amdgcn_mfma_f32_16x16x32_bf16(af[mi], bf[ni], acc[mi][ni], 0, 0, 0);
        }
    }
#pragma unroll
    for (int mi = 0; mi < 4; ++mi)
#pragma unroll
        for (int ni = 0; ni < 2; ++ni)
#pragma unroll
            for (int r = 0; r < 4; ++r) {
                int m = wm * 64 + mi * 16 + quad * 4 + r;
                int n = wn * 32 + ni * 16 + l15;
                float c = acc[mi][ni][r];
                if (MODE == 1) {
                    atomicAdd(&out[(size_t)s_tok[m] * 1024 + n0 + n], c * s_w[m]);
                } else if (MODE == 2) {
                    out[((size_t)((e_base + z) * (Bb * CAPk) + bm0 + m)) * 1024 + n0 + n] = c * s_w[m];
                } else {
                    out[(size_t)(out_row0 + bm0 + m) * 1024 + n0 + n] = c;
                }
            }
}

// ---------------- host launcher ----------------

extern "C" void kernel_launch(void* const* d_in, const int* in_sizes, int n_in,
                              void* d_out, int out_size, void* d_ws, size_t ws_size,
                              hipStream_t stream) {
    const float* hidden   = (const float*)d_in[0];
    const float* hsu      = (const float*)d_in[1];
    const float* timestep = (const float*)d_in[2];
    const float* gate_w   = (const float*)d_in[3];
    const float* gate_up  = (const float*)d_in[4];
    const float* down     = (const float*)d_in[5];
    const float* sh_gu    = (const float*)d_in[6];
    const float* sh_dn    = (const float*)d_in[7];
    float* out = (float*)d_out;

    char* p = (char*)d_ws;
    auto alloc = [&](size_t bytes) { char* r = p; p += (bytes + 255) & ~(size_t)255; return r; };
    float* scores    = (float*)alloc((size_t)Bb * Ee * Ss * 4);
    int*   rank      = (int*)  alloc((size_t)Bb * Ee * Ss * 4);
    int*   slot_token= (int*)  alloc((size_t)Ee * Bb * CAPk * 4);
    float* slot_w    = (float*)alloc((size_t)Ee * Bb * CAPk * 4);
    int*   cnt       = (int*)  alloc((size_t)Bb * Ss * 4);
    int*   inv       = (int*)  alloc((size_t)Bb * Ss * 16 * 4);
    u16*   Xb        = (u16*)  alloc((size_t)16384 * 1024 * 2);   // hidden in bf16 (32 MB)
    char* phase = p;
    long long avail = (long long)((char*)d_ws + ws_size - phase);
    if (avail < 0) avail = 0;

    const long long eo_bytes     = (long long)32768 * 1024 * 4;                    // 134 MB
    const long long per_e        = ((long long)2048 * 1024 + 1024 * 1024 +
                                    (long long)2048 * 1024) * 2;                   // 10 MB
    const long long shared_fixed = ((long long)2048 * 1024 + 1024 * 1024) * 2;     // 6 MB
    const long long fast_need    = ((long long)16 * 2048 * 1024 +   // Wt1r
                                    (long long)16 * 1024 * 1024 +   // Wt2r
                                    (long long)16 * 2048 * 1024 +   // actR
                                    (long long)2048 * 1024 +        // Wt1s
                                    (long long)1024 * 1024) * 2;    // Wt2s   = 166 MB

    // --- router pipeline ---
    conv_router<<<16384 + (Bb * Ss) / 64, 256, 0, stream>>>(hidden, Xb, hsu, gate_w,
                                                            timestep, scores);
    topk_kernel<<<Bb * Ee, 1024, 0, stream>>>(scores, rank);
    route_build<<<(Bb * Ss) / 256, 256, 0, stream>>>(scores, rank, slot_token, slot_w,
                                                     cnt, inv);

    bool use_eo = (avail >= eo_bytes + (per_e > (shared_fixed + (long long)128 * 2048)
                                        ? per_e : (shared_fixed + (long long)128 * 2048)));
    bool fast   = use_eo && (avail - eo_bytes >= fast_need);

    if (fast) {
        float* eo = (float*)phase;
        char* ph2 = phase + eo_bytes;
        u16* Wt1r = (u16*)ph2;                              // 64 MB
        u16* Wt2r = Wt1r + (size_t)16 * 2048 * 1024;        // 32 MB
        u16* actR = Wt2r + (size_t)16 * 1024 * 1024;        // 64 MB
        u16* Wt1s = actR + (size_t)16 * 2048 * 1024;        // 4 MB
        u16* Wt2s = Wt1s + (size_t)2048 * 1024;             // 2 MB
        u16* actS = Wt1r;                                   // alias: Wt1r dead after routed gemm1

        transpose_all<<<13056, 256, 0, stream>>>(gate_up, down, sh_gu, sh_dn,
                                                 Wt1r, Wt2r, Wt1s, Wt2s);
        // routed gemm1: 4 dispatches x 4 experts (2 XCDs per expert)
        for (int e0 = 0; e0 < 16; e0 += 4)
            gemm1_flat<true, true><<<512, 512, 0, stream>>>(
                Xb, Wt1r, actR, slot_token, e0, 4);
        // routed gemm2: 2 dispatches x 8 experts (1 XCD per expert)
        gemm2_flat<2><<<1024, 512, 0, stream>>>(actR, Wt2r, slot_w, eo, 0, 8);
        gemm2_flat<2><<<1024, 512, 0, stream>>>(actR, Wt2r, slot_w, eo, 8, 8);
        // shared expert: 2+2 dispatches, per-XCD m-chunks
        gemm1_flat<false, false><<<512, 512, 0, stream>>>(
            Xb, Wt1s, actS, nullptr, 0, 64);
        gemm1_flat<false, false><<<512, 512, 0, stream>>>(
            Xb, Wt1s, actS, nullptr, 64, 64);
        gemm2_flat<0><<<512, 512, 0, stream>>>(actS, Wt2s, nullptr, out, 0, 64);
        gemm2_flat<0><<<512, 512, 0, stream>>>(actS, Wt2s, nullptr, out, 64, 64);
        // dense combine
        combine_kernel<<<Bb * Ss, 256, 0, stream>>>(cnt, inv, eo, out);
    } else if (use_eo) {
        // chunked eo path (tight workspace)
        float* eo = (float*)phase;
        char* ph2 = phase + eo_bytes;
        long long avail2 = avail - eo_bytes;
        {
            int g = (int)(avail2 / per_e);
            if (g < 1) g = 1;
            if (g > Ee) g = Ee;
            u16* Wt1r = (u16*)ph2;
            u16* Wt2r = Wt1r + (size_t)g * 2048 * 1024;
            u16* actR = Wt2r + (size_t)g * 1024 * 1024;
            for (int e0 = 0; e0 < Ee; e0 += g) {
                int cg = Ee - e0; if (cg > g) cg = g;
                transpose_bf16<<<dim3(32, 16, cg), 256, 0, stream>>>(
                    gate_up + (size_t)e0 * 2097152, Wt1r, 2048, 2097152, 2097152);
                transpose_bf16<<<dim3(16, 16, cg), 256, 0, stream>>>(
                    down + (size_t)e0 * 1048576, Wt2r, 1024, 1048576, 1048576);
                gemm1_mfma<true, true><<<dim3(8, 16, cg), 512, 0, stream>>>(
                    Xb, 0, 2048, Wt1r, actR, slot_token, e0);
                gemm2_mfma<2><<<dim3(8, 16, cg), 512, 0, stream>>>(
                    actR, 2048, Wt2r, slot_token, slot_w, eo, 0, e0);
            }
        }
        {
            u16* Wt1s = (u16*)ph2;
            u16* Wt2s = Wt1s + (size_t)2048 * 1024;
            u16* actS = Wt2s + (size_t)1024 * 1024;
            long long room = (avail2 - shared_fixed) / 2048;   // act rows
            room &= ~127LL;
            int R = (int)(room > 16384 ? 16384 : room);
            if (R < 128) R = 128;
            transpose_bf16<<<dim3(32, 16, 1), 256, 0, stream>>>(sh_gu, Wt1s, 2048, 0, 0);
            transpose_bf16<<<dim3(16, 16, 1), 256, 0, stream>>>(sh_dn, Wt2s, 1024, 0, 0);
            for (int r0 = 0; r0 < Bb * Ss; r0 += R) {
                int cur = Bb * Ss - r0; if (cur > R) cur = R;
                gemm1_mfma<false, false><<<dim3(8, cur / 128, 1), 512, 0, stream>>>(
                    Xb, r0, 0, Wt1s, actS, nullptr, 0);
                gemm2_mfma<0><<<dim3(8, cur / 128, 1), 512, 0, stream>>>(
                    actS, 0, Wt2s, nullptr, nullptr, out, r0, 0);
            }
        }
        combine_kernel<<<Bb * Ss, 256, 0, stream>>>(cnt, inv, eo, out);
    } else {
        // legacy fallback: shared phase writes out, routed scatters atomically
        {
            u16* Wt1s = (u16*)phase;
            u16* Wt2s = Wt1s + (size_t)2048 * 1024;
            u16* actS = Wt2s + (size_t)1024 * 1024;
            long long room = (avail - shared_fixed) / 2048;
            room &= ~127LL;
            int R = (int)(room > 16384 ? 16384 : room);
            if (R < 128) R = 128;
            transpose_bf16<<<dim3(32, 16, 1), 256, 0, stream>>>(sh_gu, Wt1s, 2048, 0, 0);
            transpose_bf16<<<dim3(16, 16, 1), 256, 0, stream>>>(sh_dn, Wt2s, 1024, 0, 0);
            for (int r0 = 0; r0 < Bb * Ss; r0 += R) {
                int cur = Bb * Ss - r0; if (cur > R) cur = R;
                gemm1_mfma<false, false><<<dim3(8, cur / 128, 1), 512, 0, stream>>>(
                    Xb, r0, 0, Wt1s, actS, nullptr, 0);
                gemm2_mfma<0><<<dim3(8, cur / 128, 1), 512, 0, stream>>>(
                    actS, 0, Wt2s, nullptr, nullptr, out, r0, 0);
            }
        }
        {
            int g = (int)(avail / per_e);
            if (g < 1) g = 1;
            if (g > Ee) g = Ee;
            u16* Wt1r = (u16*)phase;
            u16* Wt2r = Wt1r + (size_t)g * 2048 * 1024;
            u16* actR = Wt2r + (size_t)g * 1024 * 1024;
            for (int e0 = 0; e0 < Ee; e0 += g) {
                int cg = Ee - e0; if (cg > g) cg = g;
                transpose_bf16<<<dim3(32, 16, cg), 256, 0, stream>>>(
                    gate_up + (size_t)e0 * 2097152, Wt1r, 2048, 2097152, 2097152);
                transpose_bf16<<<dim3(16, 16, cg), 256, 0, stream>>>(
                    down + (size_t)e0 * 1048576, Wt2r, 1024, 1048576, 1048576);
                gemm1_mfma<true, true><<<dim3(8, 16, cg), 512, 0, stream>>>(
                    Xb, 0, 2048, Wt1r, actR, slot_token, e0);
                gemm2_mfma<1><<<dim3(8, 16, cg), 512, 0, stream>>>(
                    actR, 2048, Wt2r, slot_token, slot_w, out, 0, e0);
            }
        }
    }
}

// Round 9
// 756.182 us; speedup vs baseline: 1.0534x; 1.0534x over previous
//
#include <hip/hip_runtime.h>
#include <math.h>

// Problem constants
#define Bb 4
#define Ss 4096
#define Hh 1024
#define Mm 1024
#define Ee 16
#define CAPk 512            // ceil(2.0 * 4096 / 16)

typedef unsigned short u16;
typedef __attribute__((ext_vector_type(8))) short short8;
typedef __attribute__((ext_vector_type(4))) float floatx4;
typedef __attribute__((ext_vector_type(4))) unsigned short ushort4v;

__device__ __forceinline__ float silu_f(float x) {
    return x / (1.0f + expf(-x));
}

// fp32 -> bf16 (RNE)
__device__ __forceinline__ u16 f2b(float x) {
    union { float f; unsigned u; } v; v.f = x;
    unsigned r = (v.u + 0x7fffu + ((v.u >> 16) & 1u)) >> 16;
    return (u16)r;
}

// async 16B global->LDS (wave-uniform LDS base + lane*16)
__device__ __forceinline__ void gl_lds16(const void* g, void* l) {
    __builtin_amdgcn_global_load_lds((const __attribute__((address_space(1))) void*)g,
                                     (__attribute__((address_space(3))) void*)l, 16, 0, 0);
}

// ---------------- fused convert + router (proven r6/r7) ----------------
// blocks [0,256): router scores (64 tokens/block) -- first so their latency
// hides under the convert stream. blocks [256,16640): convert fp32 -> bf16.

__global__ __launch_bounds__(256)
void conv_router(const float* __restrict__ hidden, u16* __restrict__ Xb,
                 const float* __restrict__ hsu,
                 const float* __restrict__ gate_w,
                 const float* __restrict__ timestep,
                 float* __restrict__ scores) {
    const int t = threadIdx.x;
    if (blockIdx.x >= 256) {
        int i = ((blockIdx.x - 256) * 256 + t) * 4;
        float4 v = *(const float4*)(hidden + i);
        ushort4v o = { f2b(v.x), f2b(v.y), f2b(v.z), f2b(v.w) };
        *(ushort4v*)(Xb + i) = o;
        return;
    }
    __shared__ float Xs[64 * 64];   // 16 KB, swizzled 16B chunks
    __shared__ float Gs[64 * 16];   // 4 KB
    const int rbid = blockIdx.x;
    const int row0 = rbid * 64;              // token base (never crosses b)
    const int b = row0 >> 12;
    const int wave = t >> 6, lane = t & 63;
    const int e0 = wave * 4;
    const float* gw2 = gate_w + (size_t)Hh * Ee;   // [k][16] second-half rows

    // inline tlogit for this wave's 4 experts
    float tl0 = 0.f, tl1 = 0.f, tl2 = 0.f, tl3 = 0.f;
    {
        const float* tsrow = timestep + (size_t)b * Hh;
#pragma unroll
        for (int j = 0; j < 16; ++j) {
            int h = lane + 64 * j;
            float tv = tsrow[h];
            const float* gw = gate_w + (size_t)h * Ee + e0;
            tl0 += tv * gw[0]; tl1 += tv * gw[1]; tl2 += tv * gw[2]; tl3 += tv * gw[3];
        }
#pragma unroll
        for (int off = 32; off; off >>= 1) {
            tl0 += __shfl_xor(tl0, off); tl1 += __shfl_xor(tl1, off);
            tl2 += __shfl_xor(tl2, off); tl3 += __shfl_xor(tl3, off);
        }
    }

    float acc0 = 0.f, acc1 = 0.f, acc2 = 0.f, acc3 = 0.f;

    for (int k0 = 0; k0 < Hh; k0 += 64) {
        __syncthreads();
#pragma unroll
        for (int r = 0; r < 4; ++r) {
            int tok = r * 16 + (t >> 4);
            int cslot = t & 15;                 // dest 16B slot within row
            int g = cslot ^ (tok & 15);         // source chunk (swizzle via source)
            const float* src = hsu + (size_t)(row0 + tok) * Hh + k0 + g * 4;
            char* dst = (char*)Xs + r * 4096 + wave * 1024;   // wave-uniform
            gl_lds16(src, dst);
        }
        {
            const float* src = gw2 + (size_t)k0 * Ee + t * 4;
            char* dst = (char*)Gs + wave * 1024;
            gl_lds16(src, dst);
        }
        __syncthreads();
#pragma unroll
        for (int kk = 0; kk < 64; kk += 4) {
            int slot = (kk >> 2) ^ (lane & 15);
            float4 a = *(const float4*)&Xs[lane * 64 + slot * 4];
            float4 g0 = *(const float4*)&Gs[(kk + 0) * Ee + e0];
            float4 g1 = *(const float4*)&Gs[(kk + 1) * Ee + e0];
            float4 g2 = *(const float4*)&Gs[(kk + 2) * Ee + e0];
            float4 g3 = *(const float4*)&Gs[(kk + 3) * Ee + e0];
            acc0 += a.x * g0.x; acc0 += a.y * g1.x; acc0 += a.z * g2.x; acc0 += a.w * g3.x;
            acc1 += a.x * g0.y; acc1 += a.y * g1.y; acc1 += a.z * g2.y; acc1 += a.w * g3.y;
            acc2 += a.x * g0.z; acc2 += a.y * g1.z; acc2 += a.z * g2.z; acc2 += a.w * g3.z;
            acc3 += a.x * g0.w; acc3 += a.y * g1.w; acc3 += a.z * g2.w; acc3 += a.w * g3.w;
        }
    }
    const int s = (row0 + lane) & (Ss - 1);
    float l0 = acc0 + tl0;
    float l1 = acc1 + tl1;
    float l2 = acc2 + tl2;
    float l3 = acc3 + tl3;
    scores[((size_t)(b * Ee + e0 + 0)) * Ss + s] = 1.f / (1.f + expf(-l0));
    scores[((size_t)(b * Ee + e0 + 1)) * Ss + s] = 1.f / (1.f + expf(-l1));
    scores[((size_t)(b * Ee + e0 + 2)) * Ss + s] = 1.f / (1.f + expf(-l2));
    scores[((size_t)(b * Ee + e0 + 3)) * Ss + s] = 1.f / (1.f + expf(-l3));
}

// Radix top-k, 1024 threads (4 elems/thread), wave-parallel scans.
// Output: dense rank[be][s] = capacity slot (or -1 if not selected).
__global__ __launch_bounds__(1024)
void topk_kernel(const float* __restrict__ scores,
                 int* __restrict__ rank) {
    const int be = blockIdx.x;
    const float* sc = scores + (size_t)be * Ss;
    int* rk = rank + (size_t)be * Ss;
    const int t = threadIdx.x;
    const int lane = t & 63, w = t >> 6;     // 16 waves
    __shared__ unsigned hist[256];
    __shared__ unsigned wtot[16];
    __shared__ unsigned sh_prefix;
    __shared__ int sh_need;
    __shared__ unsigned cnt_gt;

#pragma unroll
    for (int i = 0; i < 4; ++i) rk[t * 4 + i] = -1;

    unsigned vu[4];
#pragma unroll
    for (int i = 0; i < 4; ++i) vu[i] = __float_as_uint(sc[t * 4 + i]);

    unsigned prefix = 0;
    int need = CAPk;
    for (int pass = 0; pass < 4; ++pass) {
        const int shift = 24 - 8 * pass;
        if (t < 256) hist[t] = 0;
        __syncthreads();
#pragma unroll
        for (int i = 0; i < 4; ++i) {
            unsigned u = vu[i];
            bool ok = (pass == 0) || ((u >> (shift + 8)) == prefix);
            if (ok) atomicAdd(&hist[(u >> shift) & 255u], 1u);
        }
        __syncthreads();
        unsigned hval = (t < 256) ? hist[t] : 0u;
        unsigned s = hval;
#pragma unroll
        for (int d = 1; d < 64; d <<= 1) {
            unsigned o = __shfl_down(s, d);
            if (lane + d < 64) s += o;
        }
        if (lane == 0 && w < 4) wtot[w] = s;
        __syncthreads();
        if (t < 256) {
#pragma unroll
            for (int w2 = 0; w2 < 4; ++w2)
                if (w2 > w) s += wtot[w2];
            unsigned Snext = s - hval;
            if (s >= (unsigned)need && Snext < (unsigned)need) {
                sh_prefix = (prefix << 8) | (unsigned)t;
                sh_need = need - (int)Snext;
            }
        }
        __syncthreads();
        prefix = sh_prefix;
        need = sh_need;
        __syncthreads();
    }
    const unsigned T = prefix;
    const int need_eq = need;
    const unsigned ngt = (unsigned)(CAPk - need_eq);

    int myeq = 0;
#pragma unroll
    for (int i = 0; i < 4; ++i) myeq += (vu[i] == T) ? 1 : 0;
    unsigned e = (unsigned)myeq;
#pragma unroll
    for (int d = 1; d < 64; d <<= 1) {
        unsigned o = __shfl_up(e, d);
        if (lane >= d) e += o;
    }
    if (lane == 63) wtot[w] = e;
    if (t == 0) cnt_gt = 0;
    __syncthreads();
    unsigned eqr = e - (unsigned)myeq;
#pragma unroll
    for (int w2 = 0; w2 < 16; ++w2)
        if (w2 < w) eqr += wtot[w2];
#pragma unroll
    for (int i = 0; i < 4; ++i) {
        unsigned u = vu[i];
        int s = t * 4 + i;
        if (u > T) {
            unsigned slot = atomicAdd(&cnt_gt, 1u);
            rk[s] = (int)slot;
        } else if (u == T) {
            if ((int)eqr < need_eq) {
                rk[s] = (int)(ngt + eqr);
            }
            eqr++;
        }
    }
}

// Dense, atomic-free routing build: per-token normalization + slot map + inverse map.
__global__ __launch_bounds__(256)
void route_build(const float* __restrict__ scores, const int* __restrict__ rank,
                 int* __restrict__ slot_token, float* __restrict__ slot_w,
                 int* __restrict__ cnt, int* __restrict__ inv) {
    const int token = blockIdx.x * 256 + threadIdx.x;   // 0..16383
    const int b = token >> 12, s = token & (Ss - 1);
    int rr[16];
    float gg[16];
    float sum = 0.f;
#pragma unroll
    for (int e = 0; e < 16; ++e) {
        size_t idx = (size_t)(b * Ee + e) * Ss + s;
        int r = rank[idx];
        rr[e] = r;
        float g = (r >= 0) ? scores[idx] : 0.f;
        gg[e] = g;
        sum += g;
    }
    int pos = 0;
#pragma unroll
    for (int e = 0; e < 16; ++e) {
        if (rr[e] >= 0) {
            float wv = gg[e] / (sum + 1e-12f);
            int o = (e * Bb + b) * CAPk + rr[e];
            slot_token[o] = token;
            slot_w[o] = wv;
            inv[token * 16 + pos] = o;
            ++pos;
        }
    }
    cnt[token] = pos;
}

// dedicated high-occupancy combine: out[token] += sum_j eo[slot_j]
__global__ __launch_bounds__(256)
void combine_kernel(const int* __restrict__ cnt, const int* __restrict__ inv,
                    const float* __restrict__ eo, float* __restrict__ out) {
    const int token = blockIdx.x;           // 16384
    const int k = cnt[token];               // wave-uniform scalar
    if (k == 0) return;
    const int col = threadIdx.x * 4;
    const size_t rowoff = (size_t)token * 1024 + col;
    float4 acc = *(const float4*)(out + rowoff);
    for (int j = 0; j < k; ++j) {
        int slot = inv[token * 16 + j];     // wave-uniform
        float4 v = *(const float4*)(eo + (size_t)slot * 1024 + col);
        acc.x += v.x; acc.y += v.y; acc.z += v.z; acc.w += v.w;
    }
    *(float4*)(out + rowoff) = acc;
}

// ---------------- transposes (proven r5/r6) ----------------
// 64x64 tile fp32 [K][N] -> bf16 [N][K] (K total = 1024)

__device__ __forceinline__ void tpose_body(const float* __restrict__ Ws, u16* __restrict__ Wd,
                                           int N, int n0, int k0, float tile[64][65], int t) {
    int lr = t >> 4, lc = (t & 15) * 4;   // 16 rows/round x 16 float4 cols
#pragma unroll
    for (int i = 0; i < 4; ++i) {
        float4 v = *(const float4*)&Ws[(size_t)(k0 + lr + i * 16) * N + n0 + lc];
        tile[lr + i * 16][lc + 0] = v.x;
        tile[lr + i * 16][lc + 1] = v.y;
        tile[lr + i * 16][lc + 2] = v.z;
        tile[lr + i * 16][lc + 3] = v.w;
    }
    __syncthreads();
    int on = t >> 2;            // output n row 0..63
    int ok0 = (t & 3) * 16;     // 16 k elems per thread
    u16 buf[16];
#pragma unroll
    for (int j = 0; j < 16; ++j) buf[j] = f2b(tile[ok0 + j][on]);
    u16* dp = &Wd[(size_t)(n0 + on) * 1024 + k0 + ok0];
    *(short8*)(dp) = *(short8*)&buf[0];
    *(short8*)(dp + 8) = *(short8*)&buf[8];
}

__global__ __launch_bounds__(256)
void transpose_bf16(const float* __restrict__ W, u16* __restrict__ Wt,
                    int N, size_t zsrc, size_t zdst) {
    __shared__ float tile[64][65];
    int n0 = blockIdx.x * 64, k0 = blockIdx.y * 64, z = blockIdx.z;
    tpose_body(W + (size_t)z * zsrc, Wt + (size_t)z * zdst, N, n0, k0, tile, threadIdx.x);
}

// All four weight transposes in ONE launch (fast path).
__global__ __launch_bounds__(256)
void transpose_all(const float* __restrict__ gate_up, const float* __restrict__ down,
                   const float* __restrict__ sh_gu, const float* __restrict__ sh_dn,
                   u16* __restrict__ Wt1r, u16* __restrict__ Wt2r,
                   u16* __restrict__ Wt1s, u16* __restrict__ Wt2s) {
    __shared__ float tile[64][65];
    const int id = blockIdx.x;
    const float* Ws; u16* Wd; int N, n0, k0;
    if (id < 8192) {                       // gate_up: 16 experts x (32 n x 16 k)
        int z = id >> 9, r = id & 511;
        n0 = (r & 31) * 64; k0 = (r >> 5) * 64; N = 2048;
        Ws = gate_up + (size_t)z * 2097152; Wd = Wt1r + (size_t)z * 2097152;
    } else if (id < 12288) {               // down: 16 experts x (16 n x 16 k)
        int i2 = id - 8192; int z = i2 >> 8, r = i2 & 255;
        n0 = (r & 15) * 64; k0 = (r >> 4) * 64; N = 1024;
        Ws = down + (size_t)z * 1048576; Wd = Wt2r + (size_t)z * 1048576;
    } else if (id < 12800) {               // shared gate_up: 32 n x 16 k
        int r = id - 12288;
        n0 = (r & 31) * 64; k0 = (r >> 5) * 64; N = 2048;
        Ws = sh_gu; Wd = Wt1s;
    } else {                               // shared down: 16 n x 16 k
        int r = id - 12800;
        n0 = (r & 15) * 64; k0 = (r >> 4) * 64; N = 1024;
        Ws = sh_dn; Wd = Wt2s;
    }
    tpose_body(Ws, Wd, N, n0, k0, tile, threadIdx.x);
}

// ---------------- MFMA GEMMs ----------------
// 512-thread / 8-wave blocks, 128M x 128N block tile (2 M-waves x 4 N-waves of 64x32),
// BK=64, global_load_lds w16, XOR swizzle.
// MERGED kernels: one dispatch covers routed (L<2048: 16 experts x 16m x 8n, XCD-affine
// L&7 -> expert) + shared (L>=2048: each XCD owns a contiguous 2048-row m-slice).
// Rationale (r7 evidence): 10 GEMM dispatches -> 2 removes per-dispatch block-wave
// tails (~40us K-loop each) and inter-dispatch bubbles.

__device__ __forceinline__ void stage_tile512(const u16* __restrict__ grow, int k0,
                                              u16* lds, int t) {
#pragma unroll
    for (int r = 0; r < 2; ++r) {
        int ci = r * 512 + t;                  // 16B chunk index 0..1023
        int m = ci >> 3;                       // row 0..127
        int c = (ci & 7) ^ (m & 7);            // source chunk (swizzle via source)
        const u16* src = grow + (size_t)m * 1024 + k0 + c * 8;
        u16* dst = lds + ((r * 8192 + (t >> 6) * 1024) >> 1);  // wave-uniform
        gl_lds16(src, dst);
    }
}

__device__ __forceinline__ void stage_rows512(const u16* __restrict__ A, const int* rid,
                                              int k0, u16* lds, int t) {
#pragma unroll
    for (int r = 0; r < 2; ++r) {
        int ci = r * 512 + t;
        int m = ci >> 3;
        int c = (ci & 7) ^ (m & 7);
        const u16* src = A + (size_t)rid[r] * 1024 + k0 + c * 8;
        u16* dst = lds + ((r * 8192 + (t >> 6) * 1024) >> 1);  // wave-uniform
        gl_lds16(src, dst);
    }
}

// grid = 3072. L<2048: routed (gather A from Xb, silu(c1)*c2 -> actR).
//              L>=2048: shared (A = Xb rows, c1*silu(c2) -> actS).
__global__ __launch_bounds__(512, 4)
void gemm1_merged(const u16* __restrict__ Xb,
                  const u16* __restrict__ Wt1r, const u16* __restrict__ Wt1s,
                  u16* __restrict__ actR, u16* __restrict__ actS,
                  const int* __restrict__ slot_token) {
    __shared__ u16 lA[128 * 64];
    __shared__ u16 lB1[128 * 64];
    __shared__ u16 lB2[128 * 64];
    const int t = threadIdx.x;
    const int L = blockIdx.x;
    const bool routed = L < 2048;
    int bm0, n0, out_base;
    const u16 *B1, *B2;
    u16* actp;
    int z = 0;
    if (routed) {
        int x = L & 7, j = L >> 3;           // j in 0..255
        z = x + 8 * (j >> 7);                // experts 0-7 then 8-15
        int j2 = j & 127;
        bm0 = (j2 >> 3) << 7;                // 16 m-tiles
        n0 = (j2 & 7) << 7;                  // 8 n-tiles
        B1 = Wt1r + ((size_t)z * 2048 + n0) * 1024;
        B2 = B1 + (size_t)1024 * 1024;
        out_base = z * 2048 + bm0;
        actp = actR;
    } else {
        int l2 = L - 2048;
        int x = l2 & 7, j = l2 >> 3;         // j in 0..127
        bm0 = ((x << 4) + (j >> 3)) << 7;    // XCD-contiguous m-slice
        n0 = (j & 7) << 7;
        B1 = Wt1s + (size_t)n0 * 1024;
        B2 = B1 + (size_t)1024 * 1024;
        out_base = bm0;
        actp = actS;
    }
    const int lane = t & 63;
    const int wv = t >> 6;
    const int wm = wv & 1, wn = wv >> 1;     // 2 M-waves x 4 N-waves
    const int quad = lane >> 4, l15 = lane & 15;

    int rid[2];
#pragma unroll
    for (int r = 0; r < 2; ++r) {
        int m = (t >> 3) + 64 * r;
        rid[r] = routed ? slot_token[z * (Bb * CAPk) + bm0 + m] : (bm0 + m);
    }

    floatx4 zero4 = {0.f, 0.f, 0.f, 0.f};
    floatx4 acc1[4][2], acc2[4][2];          // 64 AGPRs total
#pragma unroll
    for (int i = 0; i < 4; ++i)
#pragma unroll
        for (int j2 = 0; j2 < 2; ++j2) { acc1[i][j2] = zero4; acc2[i][j2] = zero4; }

    for (int k0 = 0; k0 < 1024; k0 += 64) {
        __syncthreads();
        stage_rows512(Xb, rid, k0, lA, t);
        stage_tile512(B1, k0, lB1, t);
        stage_tile512(B2, k0, lB2, t);
        __syncthreads();
#pragma unroll
        for (int kc = 0; kc < 2; ++kc) {
            short8 af[4], bf1[2], bf2[2];
#pragma unroll
            for (int mi = 0; mi < 4; ++mi) {
                int m = wm * 64 + mi * 16 + l15;
                int off = m * 64 + (((kc * 4 + quad) ^ (m & 7)) * 8);
                af[mi] = *(const short8*)&lA[off];
            }
#pragma unroll
            for (int ni = 0; ni < 2; ++ni) {
                int n = wn * 32 + ni * 16 + l15;
                int off = n * 64 + (((kc * 4 + quad) ^ (n & 7)) * 8);
                bf1[ni] = *(const short8*)&lB1[off];
                bf2[ni] = *(const short8*)&lB2[off];
            }
#pragma unroll
            for (int mi = 0; mi < 4; ++mi)
#pragma unroll
                for (int ni = 0; ni < 2; ++ni) {
                    acc1[mi][ni] = __builtin_amdgcn_mfma_f32_16x16x32_bf16(af[mi], bf1[ni], acc1[mi][ni], 0, 0, 0);
                    acc2[mi][ni] = __builtin_amdgcn_mfma_f32_16x16x32_bf16(af[mi], bf2[ni], acc2[mi][ni], 0, 0, 0);
                }
        }
    }
#pragma unroll
    for (int mi = 0; mi < 4; ++mi)
#pragma unroll
        for (int ni = 0; ni < 2; ++ni)
#pragma unroll
            for (int r = 0; r < 4; ++r) {
                int m = wm * 64 + mi * 16 + quad * 4 + r;
                int n = wn * 32 + ni * 16 + l15;
                float c1 = acc1[mi][ni][r], c2 = acc2[mi][ni][r];
                float v = routed ? silu_f(c1) * c2 : c1 * silu_f(c2);
                actp[(size_t)(out_base + m) * 1024 + n0 + n] = f2b(v);
            }
}

// grid = 3072. L<2048: routed (actR x Wt2r -> weighted eo). L>=2048: shared (actS x Wt2s -> out).
__global__ __launch_bounds__(512, 4)
void gemm2_merged(const u16* __restrict__ actR, const u16* __restrict__ actS,
                  const u16* __restrict__ Wt2r, const u16* __restrict__ Wt2s,
                  const float* __restrict__ slot_w,
                  float* __restrict__ eo, float* __restrict__ out) {
    __shared__ u16 lA[128 * 64];
    __shared__ u16 lB[128 * 64];
    __shared__ float s_w[128];
    const int t = threadIdx.x;
    const int L = blockIdx.x;
    const bool routed = L < 2048;
    int bm0, n0, row_base;
    const u16 *Arow, *Brow;
    if (routed) {
        int x = L & 7, j = L >> 3;
        int z = x + 8 * (j >> 7);
        int j2 = j & 127;
        bm0 = (j2 >> 3) << 7;
        n0 = (j2 & 7) << 7;
        row_base = z * 2048 + bm0;
        Arow = actR + (size_t)row_base * 1024;
        Brow = Wt2r + ((size_t)z * 1024 + n0) * 1024;
        if (t < 128) s_w[t] = slot_w[row_base + t];
    } else {
        int l2 = L - 2048;
        int x = l2 & 7, j = l2 >> 3;
        bm0 = ((x << 4) + (j >> 3)) << 7;
        n0 = (j & 7) << 7;
        row_base = bm0;
        Arow = actS + (size_t)bm0 * 1024;
        Brow = Wt2s + (size_t)n0 * 1024;
    }
    const int lane = t & 63;
    const int wv = t >> 6;
    const int wm = wv & 1, wn = wv >> 1;
    const int quad = lane >> 4, l15 = lane & 15;

    floatx4 zero4 = {0.f, 0.f, 0.f, 0.f};
    floatx4 acc[4][2];                       // 32 AGPRs
#pragma unroll
    for (int i = 0; i < 4; ++i)
#pragma unroll
        for (int j2 = 0; j2 < 2; ++j2) acc[i][j2] = zero4;

    for (int k0 = 0; k0 < 1024; k0 += 64) {
        __syncthreads();
        stage_tile512(Arow, k0, lA, t);
        stage_tile512(Brow, k0, lB, t);
        __syncthreads();
#pragma unroll
        for (int kc = 0; kc < 2; ++kc) {
            short8 af[4], bf[2];
#pragma unroll
            for (int mi = 0; mi < 4; ++mi) {
                int m = wm * 64 + mi * 16 + l15;
                int off = m * 64 + (((kc * 4 + quad) ^ (m & 7)) * 8);
                af[mi] = *(const short8*)&lA[off];
            }
#pragma unroll
            for (int ni = 0; ni < 2; ++ni) {
                int n = wn * 32 + ni * 16 + l15;
                int off = n * 64 + (((kc * 4 + quad) ^ (n & 7)) * 8);
                bf[ni] = *(const short8*)&lB[off];
            }
#pragma unroll
            for (int mi = 0; mi < 4; ++mi)
#pragma unroll
                for (int ni = 0; ni < 2; ++ni)
                    acc[mi][ni] = __builtin_amdgcn_mfma_f32_16x16x32_bf16(af[mi], bf[ni], acc[mi][ni], 0, 0, 0);
        }
    }
#pragma unroll
    for (int mi = 0; mi < 4; ++mi)
#pragma unroll
        for (int ni = 0; ni < 2; ++ni)
#pragma unroll
            for (int r = 0; r < 4; ++r) {
                int m = wm * 64 + mi * 16 + quad * 4 + r;
                int n = wn * 32 + ni * 16 + l15;
                float c = acc[mi][ni][r];
                if (routed) {
                    eo[(size_t)(row_base + m) * 1024 + n0 + n] = c * s_w[m];
                } else {
                    out[(size_t)(row_base + m) * 1024 + n0 + n] = c;
                }
            }
}

// ---- legacy 3D-grid kernels (fallback paths only) ----

template <bool SILU_FIRST, bool GATHER>
__global__ __launch_bounds__(512, 4)
void gemm1_mfma(const u16* __restrict__ A, int a_row0, int zstride,
                const u16* __restrict__ W1t, u16* __restrict__ act,
                const int* __restrict__ slot_token, int e_base) {
    __shared__ u16 lA[128 * 64];
    __shared__ u16 lB1[128 * 64];
    __shared__ u16 lB2[128 * 64];
    const int t = threadIdx.x;
    const int n0 = blockIdx.x * 128;
    const int bm0 = blockIdx.y * 128;
    const int z = blockIdx.z;
    const int zb = z * zstride;
    const u16* B1row = W1t + ((size_t)z * 2048 + n0) * 1024;
    const u16* B2row = B1row + (size_t)1024 * 1024;
    const int lane = t & 63;
    const int wv = t >> 6;
    const int wm = wv & 1, wn = wv >> 1;
    const int quad = lane >> 4, l15 = lane & 15;

    int rid[2];
#pragma unroll
    for (int r = 0; r < 2; ++r) {
        int m = (t >> 3) + 64 * r;
        rid[r] = GATHER ? slot_token[(e_base + z) * (Bb * CAPk) + bm0 + m]
                        : (a_row0 + zb + bm0 + m);
    }

    floatx4 zero4 = {0.f, 0.f, 0.f, 0.f};
    floatx4 acc1[4][2], acc2[4][2];
#pragma unroll
    for (int i = 0; i < 4; ++i)
#pragma unroll
        for (int j = 0; j < 2; ++j) { acc1[i][j] = zero4; acc2[i][j] = zero4; }

    for (int k0 = 0; k0 < 1024; k0 += 64) {
        __syncthreads();
        stage_rows512(A, rid, k0, lA, t);
        stage_tile512(B1row, k0, lB1, t);
        stage_tile512(B2row, k0, lB2, t);
        __syncthreads();
#pragma unroll
        for (int kc = 0; kc < 2; ++kc) {
            short8 af[4], bf1[2], bf2[2];
#pragma unroll
            for (int mi = 0; mi < 4; ++mi) {
                int m = wm * 64 + mi * 16 + l15;
                int off = m * 64 + (((kc * 4 + quad) ^ (m & 7)) * 8);
                af[mi] = *(const short8*)&lA[off];
            }
#pragma unroll
            for (int ni = 0; ni < 2; ++ni) {
                int n = wn * 32 + ni * 16 + l15;
                int off = n * 64 + (((kc * 4 + quad) ^ (n & 7)) * 8);
                bf1[ni] = *(const short8*)&lB1[off];
                bf2[ni] = *(const short8*)&lB2[off];
            }
#pragma unroll
            for (int mi = 0; mi < 4; ++mi)
#pragma unroll
                for (int ni = 0; ni < 2; ++ni) {
                    acc1[mi][ni] = __builtin_amdgcn_mfma_f32_16x16x32_bf16(af[mi], bf1[ni], acc1[mi][ni], 0, 0, 0);
                    acc2[mi][ni] = __builtin_amdgcn_mfma_f32_16x16x32_bf16(af[mi], bf2[ni], acc2[mi][ni], 0, 0, 0);
                }
        }
    }
#pragma unroll
    for (int mi = 0; mi < 4; ++mi)
#pragma unroll
        for (int ni = 0; ni < 2; ++ni)
#pragma unroll
            for (int r = 0; r < 4; ++r) {
                int m = wm * 64 + mi * 16 + quad * 4 + r;
                int n = wn * 32 + ni * 16 + l15;
                float c1 = acc1[mi][ni][r], c2 = acc2[mi][ni][r];
                float v = SILU_FIRST ? silu_f(c1) * c2 : c1 * silu_f(c2);
                act[(size_t)(zb + bm0 + m) * 1024 + n0 + n] = f2b(v);
            }
}

template <int MODE>
__global__ __launch_bounds__(512, 4)
void gemm2_mfma(const u16* __restrict__ A, int zstride,
                const u16* __restrict__ W2t,
                const int* __restrict__ slot_token, const float* __restrict__ slot_w,
                float* __restrict__ out, int out_row0, int e_base) {
    __shared__ u16 lA[128 * 64];
    __shared__ u16 lB[128 * 64];
    __shared__ int s_tok[(MODE == 1) ? 128 : 1];
    __shared__ float s_w[(MODE == 1 || MODE == 2) ? 128 : 1];
    const int t = threadIdx.x;
    const int n0 = blockIdx.x * 128;
    const int bm0 = blockIdx.y * 128;
    const int z = blockIdx.z;
    const int zb = z * zstride;
    const u16* Arow = A + (size_t)(zb + bm0) * 1024;
    const u16* Brow = W2t + ((size_t)z * 1024 + n0) * 1024;
    const int lane = t & 63;
    const int wv = t >> 6;
    const int wm = wv & 1, wn = wv >> 1;
    const int quad = lane >> 4, l15 = lane & 15;

    if ((MODE == 1 || MODE == 2) && t < 128) {
        int gi = (e_base + z) * (Bb * CAPk) + bm0 + t;
        if (MODE == 1) s_tok[t] = slot_token[gi];
        s_w[t] = slot_w[gi];
    }

    floatx4 zero4 = {0.f, 0.f, 0.f, 0.f};
    floatx4 acc[4][2];
#pragma unroll
    for (int i = 0; i < 4; ++i)
#pragma unroll
        for (int j = 0; j < 2; ++j) acc[i][j] = zero4;

    for (int k0 = 0; k0 < 1024; k0 += 64) {
        __syncthreads();
        stage_tile512(Arow, k0, lA, t);
        stage_tile512(Brow, k0, lB, t);
        __syncthreads();
#pragma unroll
        for (int kc = 0; kc < 2; ++kc) {
            short8 af[4], bf[2];
#pragma unroll
            for (int mi = 0; mi < 4; ++mi) {
                int m = wm * 64 + mi * 16 + l15;
                int off = m * 64 + (((kc * 4 + quad) ^ (m & 7)) * 8);
                af[mi] = *(const short8*)&lA[off];
            }
#pragma unroll
            for (int ni = 0; ni < 2; ++ni) {
                int n = wn * 32 + ni * 16 + l15;
                int off = n * 64 + (((kc * 4 + quad) ^ (n & 7)) * 8);
                bf[ni] = *(const short8*)&lB[off];
            }
#pragma unroll
            for (int mi = 0; mi < 4; ++mi)
#pragma unroll
                for (int ni = 0; ni < 2; ++ni)
                    acc[mi][ni] = __builtin_amdgcn_mfma_f32_16x16x32_bf16(af[mi], bf[ni], acc[mi][ni], 0, 0, 0);
        }
    }
#pragma unroll
    for (int mi = 0; mi < 4; ++mi)
#pragma unroll
        for (int ni = 0; ni < 2; ++ni)
#pragma unroll
            for (int r = 0; r < 4; ++r) {
                int m = wm * 64 + mi * 16 + quad * 4 + r;
                int n = wn * 32 + ni * 16 + l15;
                float c = acc[mi][ni][r];
                if (MODE == 1) {
                    atomicAdd(&out[(size_t)s_tok[m] * 1024 + n0 + n], c * s_w[m]);
                } else if (MODE == 2) {
                    out[((size_t)((e_base + z) * (Bb * CAPk) + bm0 + m)) * 1024 + n0 + n] = c * s_w[m];
                } else {
                    out[(size_t)(out_row0 + bm0 + m) * 1024 + n0 + n] = c;
                }
            }
}

// ---------------- host launcher ----------------

extern "C" void kernel_launch(void* const* d_in, const int* in_sizes, int n_in,
                              void* d_out, int out_size, void* d_ws, size_t ws_size,
                              hipStream_t stream) {
    const float* hidden   = (const float*)d_in[0];
    const float* hsu      = (const float*)d_in[1];
    const float* timestep = (const float*)d_in[2];
    const float* gate_w   = (const float*)d_in[3];
    const float* gate_up  = (const float*)d_in[4];
    const float* down     = (const float*)d_in[5];
    const float* sh_gu    = (const float*)d_in[6];
    const float* sh_dn    = (const float*)d_in[7];
    float* out = (float*)d_out;

    char* p = (char*)d_ws;
    auto alloc = [&](size_t bytes) { char* r = p; p += (bytes + 255) & ~(size_t)255; return r; };
    float* scores    = (float*)alloc((size_t)Bb * Ee * Ss * 4);
    int*   rank      = (int*)  alloc((size_t)Bb * Ee * Ss * 4);
    int*   slot_token= (int*)  alloc((size_t)Ee * Bb * CAPk * 4);
    float* slot_w    = (float*)alloc((size_t)Ee * Bb * CAPk * 4);
    int*   cnt       = (int*)  alloc((size_t)Bb * Ss * 4);
    int*   inv       = (int*)  alloc((size_t)Bb * Ss * 16 * 4);
    u16*   Xb        = (u16*)  alloc((size_t)16384 * 1024 * 2);   // hidden in bf16 (32 MB)
    char* phase = p;
    long long avail = (long long)((char*)d_ws + ws_size - phase);
    if (avail < 0) avail = 0;

    const long long eo_bytes     = (long long)32768 * 1024 * 4;                    // 134 MB
    const long long per_e        = ((long long)2048 * 1024 + 1024 * 1024 +
                                    (long long)2048 * 1024) * 2;                   // 10 MB
    const long long shared_fixed = ((long long)2048 * 1024 + 1024 * 1024) * 2;     // 6 MB
    // fast path: Wt1r + Wt2r + actR + actS + Wt1s + Wt2s (actS separate: merged
    // gemm1 runs routed+shared concurrently)
    const long long fast_need    = ((long long)16 * 2048 * 1024 +   // Wt1r 64 MB
                                    (long long)16 * 1024 * 1024 +   // Wt2r 32 MB
                                    (long long)16 * 2048 * 1024 +   // actR 64 MB
                                    (long long)16384 * 1024 +       // actS 32 MB
                                    (long long)2048 * 1024 +        // Wt1s 4 MB
                                    (long long)1024 * 1024) * 2;    // Wt2s 2 MB = 198 MB

    bool use_eo = (avail >= eo_bytes + (per_e > (shared_fixed + (long long)128 * 2048)
                                        ? per_e : (shared_fixed + (long long)128 * 2048)));
    bool fast   = use_eo && (avail - eo_bytes >= fast_need);

    if (fast) {
        float* eo = (float*)phase;
        char* ph2 = phase + eo_bytes;
        u16* Wt1r = (u16*)ph2;
        u16* Wt2r = Wt1r + (size_t)16 * 2048 * 1024;
        u16* actR = Wt2r + (size_t)16 * 1024 * 1024;
        u16* actS = actR + (size_t)16 * 2048 * 1024;
        u16* Wt1s = actS + (size_t)16384 * 1024;
        u16* Wt2s = Wt1s + (size_t)2048 * 1024;

        // 1-2: router+convert, all weight transposes
        conv_router<<<16640, 256, 0, stream>>>(hidden, Xb, hsu, gate_w, timestep, scores);
        transpose_all<<<13056, 256, 0, stream>>>(gate_up, down, sh_gu, sh_dn,
                                                 Wt1r, Wt2r, Wt1s, Wt2s);
        // 3-4: routing
        topk_kernel<<<Bb * Ee, 1024, 0, stream>>>(scores, rank);
        route_build<<<(Bb * Ss) / 256, 256, 0, stream>>>(scores, rank, slot_token, slot_w,
                                                         cnt, inv);
        // 5-6: the two mega-GEMMs
        gemm1_merged<<<3072, 512, 0, stream>>>(Xb, Wt1r, Wt1s, actR, actS, slot_token);
        gemm2_merged<<<3072, 512, 0, stream>>>(actR, actS, Wt2r, Wt2s, slot_w, eo, out);
        // 7: dense combine
        combine_kernel<<<Bb * Ss, 256, 0, stream>>>(cnt, inv, eo, out);
    } else if (use_eo) {
        // chunked eo path (tight workspace)
        conv_router<<<16640, 256, 0, stream>>>(hidden, Xb, hsu, gate_w, timestep, scores);
        topk_kernel<<<Bb * Ee, 1024, 0, stream>>>(scores, rank);
        route_build<<<(Bb * Ss) / 256, 256, 0, stream>>>(scores, rank, slot_token, slot_w,
                                                         cnt, inv);
        float* eo = (float*)phase;
        char* ph2 = phase + eo_bytes;
        long long avail2 = avail - eo_bytes;
        {
            int g = (int)(avail2 / per_e);
            if (g < 1) g = 1;
            if (g > Ee) g = Ee;
            u16* Wt1r = (u16*)ph2;
            u16* Wt2r = Wt1r + (size_t)g * 2048 * 1024;
            u16* actR = Wt2r + (size_t)g * 1024 * 1024;
            for (int e0 = 0; e0 < Ee; e0 += g) {
                int cg = Ee - e0; if (cg > g) cg = g;
                transpose_bf16<<<dim3(32, 16, cg), 256, 0, stream>>>(
                    gate_up + (size_t)e0 * 2097152, Wt1r, 2048, 2097152, 2097152);
                transpose_bf16<<<dim3(16, 16, cg), 256, 0, stream>>>(
                    down + (size_t)e0 * 1048576, Wt2r, 1024, 1048576, 1048576);
                gemm1_mfma<true, true><<<dim3(8, 16, cg), 512, 0, stream>>>(
                    Xb, 0, 2048, Wt1r, actR, slot_token, e0);
                gemm2_mfma<2><<<dim3(8, 16, cg), 512, 0, stream>>>(
                    actR, 2048, Wt2r, slot_token, slot_w, eo, 0, e0);
            }
        }
        {
            u16* Wt1s = (u16*)ph2;
            u16* Wt2s = Wt1s + (size_t)2048 * 1024;
            u16* actS = Wt2s + (size_t)1024 * 1024;
            long long room = (avail2 - shared_fixed) / 2048;   // act rows
            room &= ~127LL;
            int R = (int)(room > 16384 ? 16384 : room);
            if (R < 128) R = 128;
            transpose_bf16<<<dim3(32, 16, 1), 256, 0, stream>>>(sh_gu, Wt1s, 2048, 0, 0);
            transpose_bf16<<<dim3(16, 16, 1), 256, 0, stream>>>(sh_dn, Wt2s, 1024, 0, 0);
            for (int r0 = 0; r0 < Bb * Ss; r0 += R) {
                int cur = Bb * Ss - r0; if (cur > R) cur = R;
                gemm1_mfma<false, false><<<dim3(8, cur / 128, 1), 512, 0, stream>>>(
                    Xb, r0, 0, Wt1s, actS, nullptr, 0);
                gemm2_mfma<0><<<dim3(8, cur / 128, 1), 512, 0, stream>>>(
                    actS, 0, Wt2s, nullptr, nullptr, out, r0, 0);
            }
        }
        combine_kernel<<<Bb * Ss, 256, 0, stream>>>(cnt, inv, eo, out);
    } else {
        // legacy fallback: shared phase writes out, routed scatters atomically
        conv_router<<<16640, 256, 0, stream>>>(hidden, Xb, hsu, gate_w, timestep, scores);
        topk_kernel<<<Bb * Ee, 1024, 0, stream>>>(scores, rank);
        route_build<<<(Bb * Ss) / 256, 256, 0, stream>>>(scores, rank, slot_token, slot_w,
                                                         cnt, inv);
        {
            u16* Wt1s = (u16*)phase;
            u16* Wt2s = Wt1s + (size_t)2048 * 1024;
            u16* actS = Wt2s + (size_t)1024 * 1024;
            long long room = (avail - shared_fixed) / 2048;
            room &= ~127LL;
            int R = (int)(room > 16384 ? 16384 : room);
            if (R < 128) R = 128;
            transpose_bf16<<<dim3(32, 16, 1), 256, 0, stream>>>(sh_gu, Wt1s, 2048, 0, 0);
            transpose_bf16<<<dim3(16, 16, 1), 256, 0, stream>>>(sh_dn, Wt2s, 1024, 0, 0);
            for (int r0 = 0; r0 < Bb * Ss; r0 += R) {
                int cur = Bb * Ss - r0; if (cur > R) cur = R;
                gemm1_mfma<false, false><<<dim3(8, cur / 128, 1), 512, 0, stream>>>(
                    Xb, r0, 0, Wt1s, actS, nullptr, 0);
                gemm2_mfma<0><<<dim3(8, cur / 128, 1), 512, 0, stream>>>(
                    actS, 0, Wt2s, nullptr, nullptr, out, r0, 0);
            }
        }
        {
            int g = (int)(avail / per_e);
            if (g < 1) g = 1;
            if (g > Ee) g = Ee;
            u16* Wt1r = (u16*)phase;
            u16* Wt2r = Wt1r + (size_t)g * 2048 * 1024;
            u16* actR = Wt2r + (size_t)g * 1024 * 1024;
            for (int e0 = 0; e0 < Ee; e0 += g) {
                int cg = Ee - e0; if (cg > g) cg = g;
                transpose_bf16<<<dim3(32, 16, cg), 256, 0, stream>>>(
                    gate_up + (size_t)e0 * 2097152, Wt1r, 2048, 2097152, 2097152);
                transpose_bf16<<<dim3(16, 16, cg), 256, 0, stream>>>(
                    down + (size_t)e0 * 1048576, Wt2r, 1024, 1048576, 1048576);
                gemm1_mfma<true, true><<<dim3(8, 16, cg), 512, 0, stream>>>(
                    Xb, 0, 2048, Wt1r, actR, slot_token, e0);
                gemm2_mfma<1><<<dim3(8, 16, cg), 512, 0, stream>>>(
                    actR, 2048, Wt2r, slot_token, slot_w, out, 0, e0);
            }
        }
    }
}